// Round 2
// baseline (813.887 us; speedup 1.0000x reference)
//
#include <hip/hip_runtime.h>
#include <hip/hip_bf16.h>

typedef __hip_bfloat16 bf16;
typedef __attribute__((ext_vector_type(8))) short short8;   // 8 bf16 frag (guide/CK-verified operand type)
typedef __attribute__((ext_vector_type(4))) float floatx4;  // MFMA C/D frag

#define HDIM 128
#define NCANON 27

// ------------------------------------------------- dtype detect (bf16 vs f32)
// bf16 data: every uint16 has a sane exponent field. f32 data: even-index
// uint16s are low mantissa bits -> random exponents (pass rate ~16%).
__global__ void detect_kernel(const unsigned short* __restrict__ xraw, int* __restrict__ flag) {
  int j = threadIdx.x;                      // 64 threads
  unsigned short u = xraw[2 * j];           // even indices only
  int e = (u >> 7) & 0xFF;
  int ok = (u == 0) || (e >= 100 && e <= 140);
  unsigned long long m = __ballot(ok);
  if (j == 0) flag[0] = (__popcll(m) >= 48) ? 1 : 0;   // 1 = bf16 storage
}

struct CanonDesc {
  const void* src[NCANON];
  int prefix[NCANON + 1];   // element offsets into arena
};

__global__ void canon_kernel(CanonDesc d, const int* __restrict__ flag,
                             bf16* __restrict__ out, int total) {
  int t = blockIdx.x * 256 + threadIdx.x;
  if (t >= total) return;
  int ti = 0;
  while (d.prefix[ti + 1] <= t) ti++;
  int off = t - d.prefix[ti];
  if (flag[0]) out[t] = ((const bf16*)d.src[ti])[off];
  else         out[t] = __float2bfloat16(((const float*)d.src[ti])[off]);
}

__global__ void emit_kernel(const bf16* __restrict__ canon_out, const int* __restrict__ flag,
                            void* __restrict__ d_out, int n) {
  int t = blockIdx.x * 256 + threadIdx.x;
  if (t >= n) return;
  if (flag[0]) ((bf16*)d_out)[t] = canon_out[t];
  else         ((float*)d_out)[t] = __bfloat162float(canon_out[t]);
}

// ---------------------------------------------------------------- CSR build
__global__ void hist_kernel(const int* __restrict__ dst, int* __restrict__ cnt, int E) {
  int e = blockIdx.x * 256 + threadIdx.x;
  if (e < E) atomicAdd(&cnt[dst[e]], 1);
}

__global__ void scan_kernel(const int* __restrict__ cnt, int* __restrict__ row_start, int n) {
  __shared__ int sh[1024];
  __shared__ int carry;
  int tid = threadIdx.x;
  if (tid == 0) carry = 0;
  __syncthreads();
  for (int base = 0; base < n; base += 1024) {
    int i = base + tid;
    int v = (i < n) ? cnt[i] : 0;
    sh[tid] = v;
    __syncthreads();
    for (int off = 1; off < 1024; off <<= 1) {
      int t = (tid >= off) ? sh[tid - off] : 0;
      __syncthreads();
      sh[tid] += t;
      __syncthreads();
    }
    int incl = sh[tid];
    if (i < n) row_start[i] = carry + incl - v;   // exclusive
    __syncthreads();
    if (tid == 1023) carry += incl;
    __syncthreads();
  }
  if (tid == 0) row_start[n] = carry;
}

__global__ void scatter_kernel(const int* __restrict__ dst, const int* __restrict__ row_start,
                               int* __restrict__ cursor, int* __restrict__ sorted, int E) {
  int e = blockIdx.x * 256 + threadIdx.x;
  if (e < E) {
    int d = dst[e];
    int pos = row_start[d] + atomicAdd(&cursor[d], 1);
    sorted[pos] = e;
  }
}

// ------------------------------------------------------------- aggregation
__global__ void aggregate_kernel(const bf16* __restrict__ h_edges, const int* __restrict__ row_start,
                                 const int* __restrict__ sorted, bf16* __restrict__ m_node, int n) {
  int node = blockIdx.x;
  if (node >= n) return;
  int col = threadIdx.x;  // 128
  int s = row_start[node], e = row_start[node + 1];
  float acc = 0.f;
  for (int p = s; p < e; p++) {
    int eid = sorted[p];
    acc += __bfloat162float(h_edges[(size_t)eid * HDIM + col]);
  }
  m_node[(size_t)node * HDIM + col] = __float2bfloat16(acc);
}

// -------------------------------------------------------- typed enc / dec
__global__ void encode_kernel(const bf16* __restrict__ x, const bf16* __restrict__ pe,
                              const int* __restrict__ types,
                              const bf16* __restrict__ W1, const bf16* __restrict__ b1,
                              const bf16* __restrict__ W2, const bf16* __restrict__ b2,
                              bf16* __restrict__ h_nodes, int n) {
  int node = blockIdx.x;
  if (node >= n) return;
  int j = threadIdx.x;  // 128
  int t = types[node];
  __shared__ float z[14];
  __shared__ float hid[HDIM];
  if (j < 6) z[j] = __bfloat162float(x[(size_t)node * 6 + j]);
  else if (j < 14) z[j] = __bfloat162float(pe[(size_t)node * 8 + (j - 6)]);
  __syncthreads();
  float acc = __bfloat162float(b1[t * HDIM + j]);
  #pragma unroll
  for (int i = 0; i < 14; i++) acc += z[i] * __bfloat162float(W1[((size_t)t * 14 + i) * HDIM + j]);
  hid[j] = fmaxf(acc, 0.f);
  __syncthreads();
  float o = __bfloat162float(b2[t * HDIM + j]);
  for (int k = 0; k < HDIM; k++) o += hid[k] * __bfloat162float(W2[((size_t)t * HDIM + k) * HDIM + j]);
  h_nodes[(size_t)node * HDIM + j] = __float2bfloat16(o);
}

__global__ void decode_kernel(const bf16* __restrict__ h_nodes, const int* __restrict__ types,
                              const bf16* __restrict__ W1, const bf16* __restrict__ b1,
                              const bf16* __restrict__ W2, const bf16* __restrict__ b2,
                              bf16* __restrict__ out, int n) {
  int node = blockIdx.x;
  if (node >= n) return;
  int j = threadIdx.x;  // 128
  int t = types[node];
  __shared__ float z[HDIM];
  __shared__ float hid[HDIM];
  z[j] = __bfloat162float(h_nodes[(size_t)node * HDIM + j]);
  __syncthreads();
  float acc = __bfloat162float(b1[t * HDIM + j]);
  for (int k = 0; k < HDIM; k++) acc += z[k] * __bfloat162float(W1[((size_t)t * HDIM + k) * HDIM + j]);
  hid[j] = fmaxf(acc, 0.f);
  __syncthreads();
  if (j < 4) {
    float o = __bfloat162float(b2[t * 4 + j]);
    for (int k = 0; k < HDIM; k++) o += hid[k] * __bfloat162float(W2[((size_t)t * HDIM + k) * 4 + j]);
    out[(size_t)node * 4 + j] = __float2bfloat16(o);
  }
}

// -------------------------------------------------- weight pre-pack (B-frag order)
// out[((ct*KS + ks)*64 + lane)*8 + j] = W[(ks*32 + quad*8 + j) * 128 + ct*16 + (lane&15)]
__global__ void pack_w(const bf16* __restrict__ W, bf16* __restrict__ out,
                       int Ksrc, int KS, int strideIn, int strideOut) {
  int idx = blockIdx.x * 256 + threadIdx.x;
  int total = 8 * KS * 64;
  if (idx >= total) return;
  int lane = idx & 63;
  int ks = (idx >> 6) % KS;
  int ct = idx / (64 * KS);
  const bf16* Ws = W + (size_t)blockIdx.y * strideIn;
  bf16* o = out + (size_t)blockIdx.y * strideOut + (size_t)idx * 8;
  int ncol = ct * 16 + (lane & 15);
  int kb = ks * 32 + ((lane >> 4) & 3) * 8;
  #pragma unroll
  for (int j = 0; j < 8; j++) {
    int k = kb + j;
    o[j] = (k < Ksrc) ? Ws[(size_t)k * HDIM + ncol] : __float2bfloat16(0.f);
  }
}

// -------------------------------------------------- generic fused 2-layer MLP (MFMA)
// out = [Z[RES_PART*128..] +] (ReLU(Z @ W1 + b1) @ W2 + b2),  Z = concat of NPARTS 128-dim rows
// BM rows/block, 256 threads (4 waves), each wave owns a 32-col output strip.
template<int NPARTS, bool ATTR4, int RES_PART, int BM>
__global__ void __launch_bounds__(256) mlp2_kernel(
    const bf16* __restrict__ p0, const int* __restrict__ idx0,
    const bf16* __restrict__ p1, const int* __restrict__ idx1,
    const bf16* __restrict__ p2, const int* __restrict__ idx2,
    const bf16* __restrict__ W1p, const bf16* __restrict__ b1v,
    const bf16* __restrict__ W2p, const bf16* __restrict__ b2v,
    bf16* __restrict__ outp, int M) {
  constexpr int RT = BM / 16;             // 16-row tiles per block
  constexpr int KS1 = NPARTS * 4;         // K-steps of 32 in GEMM1
  constexpr int SK = NPARTS * 128 + 8;    // padded Z row stride
  constexpr int HS = 136;                 // padded Hid row stride

  __shared__ bf16 Zt[BM * SK];
  __shared__ bf16 Hid[BM * HS];

  const int tid = threadIdx.x;
  const int lane = tid & 63;
  const int wave = tid >> 6;
  const int colq = lane & 15;
  const int quad = lane >> 4;
  const int row0 = blockIdx.x * BM;

  // ---- stage Z tile (gathered, zero-padded)
  if (ATTR4) {
    for (int i = tid; i < BM * 16; i += 256) {
      int row = i >> 4, seg = i & 15;
      int gr = row0 + row;
      uint4 val = {0u, 0u, 0u, 0u};
      if (seg == 0 && gr < M) {
        uint2 v = *(const uint2*)(p0 + (size_t)gr * 4);  // 4 bf16 = 8B
        val.x = v.x; val.y = v.y;
      }
      *(uint4*)(&Zt[row * SK + seg * 8]) = val;
    }
  } else {
    for (int i = tid; i < BM * NPARTS * 16; i += 256) {
      int row = i / (NPARTS * 16);
      int rem = i - row * (NPARTS * 16);
      int part = rem >> 4, seg = rem & 15;
      int gr = row0 + row;
      uint4 val = {0u, 0u, 0u, 0u};
      if (gr < M) {
        const bf16* p = (part == 0) ? p0 : ((part == 1) ? p1 : p2);
        const int* ix = (part == 0) ? idx0 : ((part == 1) ? idx1 : idx2);
        int g = ix ? ix[gr] : gr;
        val = *(const uint4*)(p + (size_t)g * HDIM + seg * 8);
      }
      *(uint4*)(&Zt[row * SK + part * 128 + seg * 8]) = val;
    }
  }
  __syncthreads();

  // ---- GEMM1: Hidden = ReLU(Z @ W1 + b1)
  floatx4 acc[RT][2];
  #pragma unroll
  for (int rt = 0; rt < RT; rt++)
    #pragma unroll
    for (int c = 0; c < 2; c++) acc[rt][c] = (floatx4){0.f, 0.f, 0.f, 0.f};

  #pragma unroll
  for (int ks = 0; ks < KS1; ks++) {
    short8 bfr0 = *(const short8*)(W1p + (((size_t)(wave * 2 + 0) * KS1 + ks) * 64 + lane) * 8);
    short8 bfr1 = *(const short8*)(W1p + (((size_t)(wave * 2 + 1) * KS1 + ks) * 64 + lane) * 8);
    #pragma unroll
    for (int rt = 0; rt < RT; rt++) {
      short8 a = *(const short8*)(&Zt[(rt * 16 + colq) * SK + ks * 32 + quad * 8]);
      acc[rt][0] = __builtin_amdgcn_mfma_f32_16x16x32_bf16(a, bfr0, acc[rt][0], 0, 0, 0);
      acc[rt][1] = __builtin_amdgcn_mfma_f32_16x16x32_bf16(a, bfr1, acc[rt][1], 0, 0, 0);
    }
  }

  // bias + ReLU, C-layout -> LDS rows (A-layout source for GEMM2)
  #pragma unroll
  for (int c = 0; c < 2; c++) {
    int col = wave * 32 + c * 16 + colq;
    float bv = __bfloat162float(b1v[col]);
    #pragma unroll
    for (int rt = 0; rt < RT; rt++)
      #pragma unroll
      for (int r = 0; r < 4; r++) {
        float v = acc[rt][c][r] + bv;
        Hid[(rt * 16 + quad * 4 + r) * HS + col] = __float2bfloat16(fmaxf(v, 0.f));
      }
  }
  __syncthreads();

  // ---- GEMM2: Out = Hidden @ W2 + b2 (+ residual from Zt)
  floatx4 acc2[RT][2];
  #pragma unroll
  for (int rt = 0; rt < RT; rt++)
    #pragma unroll
    for (int c = 0; c < 2; c++) acc2[rt][c] = (floatx4){0.f, 0.f, 0.f, 0.f};

  #pragma unroll
  for (int ks = 0; ks < 4; ks++) {
    short8 bfr0 = *(const short8*)(W2p + (((size_t)(wave * 2 + 0) * 4 + ks) * 64 + lane) * 8);
    short8 bfr1 = *(const short8*)(W2p + (((size_t)(wave * 2 + 1) * 4 + ks) * 64 + lane) * 8);
    #pragma unroll
    for (int rt = 0; rt < RT; rt++) {
      short8 a = *(const short8*)(&Hid[(rt * 16 + colq) * HS + ks * 32 + quad * 8]);
      acc2[rt][0] = __builtin_amdgcn_mfma_f32_16x16x32_bf16(a, bfr0, acc2[rt][0], 0, 0, 0);
      acc2[rt][1] = __builtin_amdgcn_mfma_f32_16x16x32_bf16(a, bfr1, acc2[rt][1], 0, 0, 0);
    }
  }

  #pragma unroll
  for (int c = 0; c < 2; c++) {
    int col = wave * 32 + c * 16 + colq;
    float bv = __bfloat162float(b2v[col]);
    #pragma unroll
    for (int rt = 0; rt < RT; rt++)
      #pragma unroll
      for (int r = 0; r < 4; r++) {
        int lrow = rt * 16 + quad * 4 + r;
        int grow = row0 + lrow;
        if (grow < M) {
          float v = acc2[rt][c][r] + bv;
          if constexpr (RES_PART >= 0)
            v += __bfloat162float(Zt[lrow * SK + RES_PART * 128 + col]);
          outp[(size_t)grow * HDIM + col] = __float2bfloat16(v);
        }
      }
  }
}

// ---------------------------------------------------------------- launcher
extern "C" void kernel_launch(void* const* d_in, const int* in_sizes, int n_in,
                              void* d_out, int out_size, void* d_ws, size_t ws_size,
                              hipStream_t stream) {
  const int* edge_index = (const int*)d_in[27];
  const int* node_types = (const int*)d_in[28];
  const int N = in_sizes[28];
  const int E = in_sizes[2] / 4;
  const int L = in_sizes[12] / HDIM;
  const int* srcI = edge_index;
  const int* dstI = edge_index + E;

  // canon arena descriptor (all 27 float tensors, element-offset prefix)
  CanonDesc cd;
  int total = 0;
  for (int i = 0; i < NCANON; i++) { cd.src[i] = d_in[i]; cd.prefix[i] = total; total += in_sizes[i]; }
  cd.prefix[NCANON] = total;

  char* wsb = (char*)d_ws;
  size_t off = 0;
  auto alloc = [&](size_t bytes) -> void* {
    void* p = wsb + off;
    off += (bytes + 255) & ~(size_t)255;
    return p;
  };
  int*  flag      = (int*)alloc(256);
  bf16* arena     = (bf16*)alloc((size_t)total * 2);
  bf16* h_nodes   = (bf16*)alloc((size_t)N * HDIM * 2);
  bf16* h_edges   = (bf16*)alloc((size_t)E * HDIM * 2);
  bf16* m_node    = (bf16*)alloc((size_t)N * HDIM * 2);
  bf16* localb    = (bf16*)alloc((size_t)N * HDIM * 2);
  bf16* canon_out = (bf16*)alloc((size_t)out_size * 2);
  int* counts     = (int*)alloc((size_t)N * 4);
  int* cursor     = (int*)alloc((size_t)N * 4);
  int* row_start  = (int*)alloc((size_t)(N + 1) * 4);
  int* sorted     = (int*)alloc((size_t)E * 4);
  bf16* eeW1p = (bf16*)alloc(16384 * 2);
  bf16* eeW2p = (bf16*)alloc(16384 * 2);
  bf16* euW1p = (bf16*)alloc((size_t)L * 49152 * 2);
  bf16* euW2p = (bf16*)alloc((size_t)L * 16384 * 2);
  bf16* nuW1p = (bf16*)alloc((size_t)L * 32768 * 2);
  bf16* nuW2p = (bf16*)alloc((size_t)L * 16384 * 2);
  bf16* fuW1p = (bf16*)alloc((size_t)L * 16384 * 2);
  bf16* fuW2p = (bf16*)alloc((size_t)L * 16384 * 2);

  // canonical bf16 views of every float tensor
  const bf16* cX     = arena + cd.prefix[0];
  const bf16* cPE    = arena + cd.prefix[1];
  const bf16* cEA    = arena + cd.prefix[2];
  const bf16* cEncW1 = arena + cd.prefix[3];
  const bf16* cEncB1 = arena + cd.prefix[4];
  const bf16* cEncW2 = arena + cd.prefix[5];
  const bf16* cEncB2 = arena + cd.prefix[6];
  const bf16* cEeW1  = arena + cd.prefix[7];
  const bf16* cEeB1  = arena + cd.prefix[8];
  const bf16* cEeW2  = arena + cd.prefix[9];
  const bf16* cEeB2  = arena + cd.prefix[10];
  const bf16* cEuW1  = arena + cd.prefix[11];
  const bf16* cEuB1  = arena + cd.prefix[12];
  const bf16* cEuW2  = arena + cd.prefix[13];
  const bf16* cEuB2  = arena + cd.prefix[14];
  const bf16* cNuW1  = arena + cd.prefix[15];
  const bf16* cNuB1  = arena + cd.prefix[16];
  const bf16* cNuW2  = arena + cd.prefix[17];
  const bf16* cNuB2  = arena + cd.prefix[18];
  const bf16* cFuW1  = arena + cd.prefix[19];
  const bf16* cFuB1  = arena + cd.prefix[20];
  const bf16* cFuW2  = arena + cd.prefix[21];
  const bf16* cFuB2  = arena + cd.prefix[22];
  const bf16* cDecW1 = arena + cd.prefix[23];
  const bf16* cDecB1 = arena + cd.prefix[24];
  const bf16* cDecW2 = arena + cd.prefix[25];
  const bf16* cDecB2 = arena + cd.prefix[26];

  detect_kernel<<<1, 64, 0, stream>>>((const unsigned short*)d_in[0], flag);
  canon_kernel<<<(total + 255) / 256, 256, 0, stream>>>(cd, flag, arena, total);

  hipMemsetAsync(counts, 0, (size_t)N * 4, stream);
  hipMemsetAsync(cursor, 0, (size_t)N * 4, stream);

  // weight packing into B-fragment order
  pack_w<<<dim3(8, 1), 256, 0, stream>>>(cEeW1, eeW1p, 4, 4, 0, 0);
  pack_w<<<dim3(8, 1), 256, 0, stream>>>(cEeW2, eeW2p, 128, 4, 0, 0);
  pack_w<<<dim3(24, L), 256, 0, stream>>>(cEuW1, euW1p, 384, 12, 384 * HDIM, 49152);
  pack_w<<<dim3(8, L), 256, 0, stream>>>(cEuW2, euW2p, 128, 4, HDIM * HDIM, 16384);
  pack_w<<<dim3(16, L), 256, 0, stream>>>(cNuW1, nuW1p, 256, 8, 256 * HDIM, 32768);
  pack_w<<<dim3(8, L), 256, 0, stream>>>(cNuW2, nuW2p, 128, 4, HDIM * HDIM, 16384);
  pack_w<<<dim3(8, L), 256, 0, stream>>>(cFuW1, fuW1p, 128, 4, HDIM * HDIM, 16384);
  pack_w<<<dim3(8, L), 256, 0, stream>>>(cFuW2, fuW2p, 128, 4, HDIM * HDIM, 16384);

  // CSR build
  hist_kernel<<<(E + 255) / 256, 256, 0, stream>>>(dstI, counts, E);
  scan_kernel<<<1, 1024, 0, stream>>>(counts, row_start, N);
  scatter_kernel<<<(E + 255) / 256, 256, 0, stream>>>(dstI, row_start, cursor, sorted, E);

  // encoders
  encode_kernel<<<N, 128, 0, stream>>>(cX, cPE, node_types, cEncW1, cEncB1, cEncW2, cEncB2, h_nodes, N);
  int egrid64 = (E + 63) / 64;
  int egrid32 = (E + 31) / 32;
  int ngrid64 = (N + 63) / 64;
  mlp2_kernel<1, true, -1, 64><<<egrid64, 256, 0, stream>>>(
      cEA, nullptr, nullptr, nullptr, nullptr, nullptr,
      eeW1p, cEeB1, eeW2p, cEeB2, h_edges, E);

  for (int l = 0; l < L; l++) {
    mlp2_kernel<3, false, 2, 32><<<egrid32, 256, 0, stream>>>(
        h_nodes, srcI, h_nodes, dstI, h_edges, nullptr,
        euW1p + (size_t)l * 49152, cEuB1 + l * HDIM,
        euW2p + (size_t)l * 16384, cEuB2 + l * HDIM, h_edges, E);
    aggregate_kernel<<<N, 128, 0, stream>>>(h_edges, row_start, sorted, m_node, N);
    mlp2_kernel<2, false, 0, 64><<<ngrid64, 256, 0, stream>>>(
        h_nodes, nullptr, m_node, nullptr, nullptr, nullptr,
        nuW1p + (size_t)l * 32768, cNuB1 + l * HDIM,
        nuW2p + (size_t)l * 16384, cNuB2 + l * HDIM, localb, N);
    mlp2_kernel<1, false, -1, 64><<<ngrid64, 256, 0, stream>>>(
        localb, nullptr, nullptr, nullptr, nullptr, nullptr,
        fuW1p + (size_t)l * 16384, cFuB1 + l * HDIM,
        fuW2p + (size_t)l * 16384, cFuB2 + l * HDIM, h_nodes, N);
  }

  decode_kernel<<<N, 128, 0, stream>>>(h_nodes, node_types, cDecW1, cDecB1, cDecW2, cDecB2,
                                       canon_out, N);
  emit_kernel<<<(out_size + 255) / 256, 256, 0, stream>>>(canon_out, flag, d_out, out_size);
  (void)n_in; (void)ws_size;
}